// Round 9
// baseline (218.066 us; speedup 1.0000x reference)
//
#include <hip/hip_runtime.h>

typedef __bf16 bf16x8 __attribute__((ext_vector_type(8)));
typedef __bf16 bf16x4 __attribute__((ext_vector_type(4)));
typedef float f32x4 __attribute__((ext_vector_type(4)));

namespace {
constexpr int Bn = 2, Cn = 64, hn = 96, wn = 96, Hn = 384, Wn = 384;
constexpr int CIN = 266;
constexpr int TM = 64;                      // pixels per workgroup tile
constexpr int SP = 296;                     // Abuf row stride (bf16): 592B
// fragment-major weight layouts (R5 form). A-frag mapping for
// mfma_f32_16x16x32_bf16: lane l supplies A[m = l&15][k = (l>>4)*8 + j].
constexpr int L1_FRAGS = 9 * 16 * 64;       // 9216
constexpr int L2_FRAGS = 8 * 16 * 64;       // 8192
constexpr int L3_FRAGS = 8 * 64;            // 512
constexpr int N_FRAGS = L1_FRAGS + L2_FRAGS + L3_FRAGS;   // 17920
constexpr int SC_OFF_BYTES = N_FRAGS * 16;                 // 286720
constexpr int B1EFF_OFF_BYTES = SC_OFF_BYTES + Bn * 3 * hn * wn * 4;
constexpr int FRAG_BLOCKS = N_FRAGS / 256;  // 70
constexpr int NPIX = Bn * hn * wn;          // 18432
constexpr int SC_BLOCKS = NPIX / 256;       // 72
}

// Halves-split Abuf column map: logical bf16 channel k (k%4==0 group) lives at
//   low half (k%8 < 4):  col = (k>>5)*16 + ((k>>3)&3)*4
//   high half (k%8 >= 4): col = 144 + same
// B-frag (8 bf16) = two b64 loads 288B apart -> compiler cannot merge to b128.
// Bank math: dword base = 20*row + 2*quad (mod 32); quad parity lands on
// disjoint odd-offset banks; residual collisions are (r, r+8) 2-way = free.

// ---------------- prep (single dispatch): weight frags + b1eff + shortcut MLP ----------------
__global__ void prep_all(const float* __restrict__ w00, const float* __restrict__ w1,
                         const float* __restrict__ w2, const float* __restrict__ b00,
                         const float* __restrict__ b1,
                         const float* __restrict__ feat, const float* __restrict__ ws1,
                         const float* __restrict__ bs1, const float* __restrict__ ws2,
                         const float* __restrict__ bs2,
                         __bf16* __restrict__ wb, float* __restrict__ b1eff,
                         float* __restrict__ sc)
{
    const int bid = blockIdx.x;
    if (bid < FRAG_BLOCKS) {
        const int f = bid * 256 + threadIdx.x;
        bf16x8 v;
        if (f < L1_FRAGS) {
            const int k0 = f >> 10;
            const int mb = (f >> 6) & 15;
            const int l  = f & 63;
            const int m  = mb * 16 + (l & 15);
            const int kb = k0 * 32 + (l >> 4) * 8;
#pragma unroll
            for (int j = 0; j < 8; j++)
                v[j] = (kb + j < CIN) ? (__bf16)w00[m * CIN + kb + j] : (__bf16)0.f;
        } else if (f < L1_FRAGS + L2_FRAGS) {
            const int g = f - L1_FRAGS;
            const int k0 = g >> 10;
            const int mb = (g >> 6) & 15;
            const int l  = g & 63;
            const int m  = mb * 16 + (l & 15);
            const int kb = k0 * 32 + (l >> 4) * 8;
#pragma unroll
            for (int j = 0; j < 8; j++) v[j] = (__bf16)w1[m * 256 + kb + j];
        } else {
            const int g = f - (L1_FRAGS + L2_FRAGS);
            const int k0 = g >> 6;
            const int l  = g & 63;
            const int m  = l & 15;
            const int kb = k0 * 32 + (l >> 4) * 8;
#pragma unroll
            for (int j = 0; j < 8; j++)
                v[j] = (m < 3) ? (__bf16)w2[m * 256 + kb + j] : (__bf16)0.f;
        }
        *(bf16x8*)(wb + f * 8) = v;
        return;
    }
    if (bid == FRAG_BLOCKS) {
        __shared__ float cb[256];
        const int o = threadIdx.x;
        cb[o] = b00[o] + 0.5f * (w00[o * CIN + 264] + w00[o * CIN + 265]);
        __syncthreads();
        float v = b1[o];
#pragma unroll 4
        for (int k = 0; k < 256; k++) v = fmaf(w1[o * 256 + k], cb[k], v);
        b1eff[o] = v;
        return;
    }
    const int t = (bid - FRAG_BLOCKS - 1) * 256 + threadIdx.x;
    if (t >= NPIX) return;
    const int b = t / (hn * wn);
    const int yx = t % (hn * wn);
    const float* fp = feat + b * Cn * hn * wn + yx;
    float f[Cn];
#pragma unroll
    for (int c = 0; c < Cn; c++) f[c] = fp[c * hn * wn];
    float o0 = bs2[0], o1 = bs2[1], o2 = bs2[2];
#pragma unroll 1
    for (int co = 0; co < Cn; co += 4) {
        float v0 = bs1[co], v1 = bs1[co + 1], v2 = bs1[co + 2], v3 = bs1[co + 3];
        const float* wr = ws1 + co * Cn;
#pragma unroll
        for (int ci = 0; ci < Cn; ci++) {
            const float fv = f[ci];
            v0 = fmaf(wr[ci], fv, v0);
            v1 = fmaf(wr[Cn + ci], fv, v1);
            v2 = fmaf(wr[2 * Cn + ci], fv, v2);
            v3 = fmaf(wr[3 * Cn + ci], fv, v3);
        }
        v0 = fmaxf(v0, 0.f); v1 = fmaxf(v1, 0.f); v2 = fmaxf(v2, 0.f); v3 = fmaxf(v3, 0.f);
#pragma unroll
        for (int u = 0; u < 4; u++) {
            const float vv = (u == 0) ? v0 : (u == 1) ? v1 : (u == 2) ? v2 : v3;
            o0 = fmaf(ws2[co + u], vv, o0);
            o1 = fmaf(ws2[Cn + co + u], vv, o1);
            o2 = fmaf(ws2[2 * Cn + co + u], vv, o2);
        }
    }
    sc[(b * 3 + 0) * hn * wn + yx] = o0;
    sc[(b * 3 + 1) * hn * wn + yx] = o1;
    sc[(b * 3 + 2) * hn * wn + yx] = o2;
}

__device__ __forceinline__ float gelu_fast(float x) {
    const float d0 = -2.302118074f;   // -2*0.7978845608*log2(e)
    const float d1 = -0.1029453754f;  // -2*0.0356774081*log2(e)
    float t = x * x;
    float a = x * fmaf(t, d1, d0);
    float e = __builtin_amdgcn_exp2f(a);
    return x * __builtin_amdgcn_rcpf(1.f + e);
}

__device__ __forceinline__ bf16x4 pack4(f32x4 x) {
    bf16x4 v;
    v[0] = (__bf16)x[0]; v[1] = (__bf16)x[1]; v[2] = (__bf16)x[2]; v[3] = (__bf16)x[3];
    return v;
}

#define MF(A, B, C) __builtin_amdgcn_mfma_f32_16x16x32_bf16((A), (B), (C), 0, 0, 0)

// load one B-frag (8 bf16) for row R, kstep k0: two b64s from the halves
#define LD1(D, R, k0) do {                                                      \
    *(bf16x4*)&D         = *(const bf16x4*)&Abuf[R][(k0) * 16 + q4];            \
    *(((bf16x4*)&D) + 1) = *(const bf16x4*)&Abuf[R][144 + (k0) * 16 + q4];      \
} while (0)

// prefetch pair (rows lane16, 16+lane16) for kstep k0
#define LDG2(P0, P1, k0) do { LD1(P0, lane16, k0); LD1(P1, 16 + lane16, k0); } while (0)

// 16 MFMAs of kstep k0: G0,G1 prefetched; G2,G3 just-in-time (covered by
// the 8 MFMAs on G0/G1). NXP: if 1, prefetch kstep knx into N0,N1.
#define GSTP(W0, W1, W2, W3, G0, G1, k0, N0, N1, knx, NXP) do {                 \
    bf16x8 Gt2, Gt3;                                                            \
    LD1(Gt2, 32 + lane16, k0);                                                  \
    LD1(Gt3, 48 + lane16, k0);                                                  \
    if (NXP) { LDG2(N0, N1, knx); }                                             \
    a00 = MF(W0, G0, a00); a01 = MF(W1, G0, a01);                               \
    a02 = MF(W2, G0, a02); a03 = MF(W3, G0, a03);                               \
    a10 = MF(W0, G1, a10); a11 = MF(W1, G1, a11);                               \
    a12 = MF(W2, G1, a12); a13 = MF(W3, G1, a13);                               \
    a20 = MF(W0, Gt2, a20); a21 = MF(W1, Gt2, a21);                             \
    a22 = MF(W2, Gt2, a22); a23 = MF(W3, Gt2, a23);                             \
    a30 = MF(W0, Gt3, a30); a31 = MF(W1, Gt3, a31);                             \
    a32 = MF(W2, Gt3, a32); a33 = MF(W3, Gt3, a33);                             \
} while (0)

#define LDW(W0, W1, W2, W3, src, kk) do {             \
    W0 = (src)[((kk) * 16 + mb0 + 0) * 64 + lane];    \
    W1 = (src)[((kk) * 16 + mb0 + 1) * 64 + lane];    \
    W2 = (src)[((kk) * 16 + mb0 + 2) * 64 + lane];    \
    W3 = (src)[((kk) * 16 + mb0 + 3) * 64 + lane];    \
} while (0)

#define ZACC4(n) a##n##0 = zf; a##n##1 = zf; a##n##2 = zf; a##n##3 = zf

__global__ __launch_bounds__(256, 3) void liif_main(
    const float* __restrict__ feat, const float* __restrict__ b1eff,
    const float* __restrict__ b2v, const __bf16* __restrict__ wb,
    const float* __restrict__ sc, float* __restrict__ out)
{
    __shared__ __align__(16) __bf16 Abuf[TM][SP];

    const int t = threadIdx.x;
    const int wv = t >> 6;
    const int lane = t & 63;
    const int lane16 = lane & 15;
    const int quad = lane >> 4;
    const int q4 = quad * 4;
    const int mb0 = wv * 4;

    // XCD swizzle: each XCD owns a contiguous Y-band (feat slice L2-resident)
    constexpr int NWG = Bn * Hn * (Wn / TM);       // 4608
    const int lt = (blockIdx.x & 7) * (NWG / 8) + (blockIdx.x >> 3);
    constexpr int TPR = Wn / TM;
    const int tx = lt % TPR;
    const int Y = (lt / TPR) % Hn;
    const int b = lt / (TPR * Hn);
    const int X0 = tx * TM;

    const float cy = -1.f + 1.f / Hn + (2.f / Hn) * (float)Y;

    const bf16x8* wf1 = (const bf16x8*)wb;
    const bf16x8* wf2 = wf1 + L1_FRAGS;
    const bf16x8* w2f = wf1 + (L1_FRAGS + L2_FRAGS);

    // layer-1 initial weight prefetch (ksteps 0,1) issued BEFORE the gather
    bf16x8 wE0, wE1, wE2, wE3, wO0, wO1, wO2, wO3;
    LDW(wE0, wE1, wE2, wE3, wf1, 0);
    LDW(wO0, wO1, wO2, wO3, wf1, 1);

    // ---------- phase 1: build grid features [64 x 288] bf16 (halves-split) ----------
    {
        const int p = lane;     // pixel in tile
        const int j = wv;       // this wave handles corner j's gather
        const int X = X0 + p;
        const float cx = -1.f + 1.f / Wn + (2.f / Wn) * (float)X;
        float rely[4], relx[4], area[4];
        int iyv[4], ixv[4];
#pragma unroll
        for (int c = 0; c < 4; c++) {
            const float vx = (c & 2) ? 1.f : -1.f;
            const float vy = (c & 1) ? 1.f : -1.f;
            float sy = fminf(fmaxf(cy + vx * (1.f / hn) + 1e-6f, -1.f + 1e-6f), 1.f - 1e-6f);
            float sx = fminf(fmaxf(cx + vy * (1.f / wn) + 1e-6f, -1.f + 1e-6f), 1.f - 1e-6f);
            float uy = ((sy + 1.f) * hn - 1.f) * 0.5f;
            float ux = ((sx + 1.f) * wn - 1.f) * 0.5f;
            int iy = min(max((int)rintf(uy), 0), hn - 1);   // round-half-even == jnp.round
            int ix = min(max((int)rintf(ux), 0), wn - 1);
            float oy = -1.f + 1.f / hn + (2.f / hn) * (float)iy;
            float ox = -1.f + 1.f / wn + (2.f / wn) * (float)ix;
            rely[c] = (cy - oy) * hn;
            relx[c] = (cx - ox) * wn;
            area[c] = fabsf(rely[c] * relx[c]) + 1e-9f;
            iyv[c] = iy; ixv[c] = ix;
        }
        const float tot = area[0] + area[1] + area[2] + area[3];
        const float wj = area[3 - j] / tot;   // LIIF area swap 0<->3, 1<->2

        if (j == 0) {  // logical k 0..7: [rel_y0, rel_x0, ..., rel_y3, rel_x3]
            bf16x4 lo, hi;
            lo[0] = (__bf16)rely[0]; lo[1] = (__bf16)relx[0];
            lo[2] = (__bf16)rely[1]; lo[3] = (__bf16)relx[1];
            hi[0] = (__bf16)rely[2]; hi[1] = (__bf16)relx[2];
            hi[2] = (__bf16)rely[3]; hi[3] = (__bf16)relx[3];
            *(bf16x4*)&Abuf[p][0]   = lo;
            *(bf16x4*)&Abuf[p][144] = hi;
        }
        // logical k = 8 + 64j + 8*c8 + cc: feat at (iy_j, ix_j) scaled by wj
        const float* fb = feat + ((b * Cn) * hn + iyv[j]) * wn + ixv[j];
#pragma unroll
        for (int c8 = 0; c8 < 8; c8++) {
            bf16x4 lo, hi;
#pragma unroll
            for (int cc = 0; cc < 4; cc++)
                lo[cc] = (__bf16)(fb[(c8 * 8 + cc) * (hn * wn)] * wj);
#pragma unroll
            for (int cc = 4; cc < 8; cc++)
                hi[cc - 4] = (__bf16)(fb[(c8 * 8 + cc) * (hn * wn)] * wj);
            const int tq = 1 + 8 * j + c8;                 // base>>3
            const int cb = (tq >> 2) * 16 + (tq & 3) * 4;
            *(bf16x4*)&Abuf[p][cb]       = lo;
            *(bf16x4*)&Abuf[p][144 + cb] = hi;
        }
        if (j == 3) {  // logical k 264..287 zero (rel_cell folded into b1eff)
            bf16x4 z;
            z[0] = (__bf16)0.f; z[1] = (__bf16)0.f; z[2] = (__bf16)0.f; z[3] = (__bf16)0.f;
            *(bf16x4*)&Abuf[p][132] = z; *(bf16x4*)&Abuf[p][276] = z;  // t=33
            *(bf16x4*)&Abuf[p][136] = z; *(bf16x4*)&Abuf[p][280] = z;  // t=34
            *(bf16x4*)&Abuf[p][140] = z; *(bf16x4*)&Abuf[p][284] = z;  // t=35
        }
    }
    __syncthreads();

    const f32x4 zf = (f32x4){0.f, 0.f, 0.f, 0.f};
    f32x4 a00, a01, a02, a03, a10, a11, a12, a13;
    f32x4 a20, a21, a22, a23, a30, a31, a32, a33;
    ZACC4(0); ZACC4(1); ZACC4(2); ZACC4(3);

    bf16x8 gE0, gE1, gO0, gO1;
    LDG2(gE0, gE1, 0);

    // ---------- layer 1: W00[256x288] x G^T, 9 ksteps ----------
    GSTP(wE0, wE1, wE2, wE3, gE0, gE1, 0, gO0, gO1, 1, 1); LDW(wE0, wE1, wE2, wE3, wf1, 2);
    GSTP(wO0, wO1, wO2, wO3, gO0, gO1, 1, gE0, gE1, 2, 1); LDW(wO0, wO1, wO2, wO3, wf1, 3);
    GSTP(wE0, wE1, wE2, wE3, gE0, gE1, 2, gO0, gO1, 3, 1); LDW(wE0, wE1, wE2, wE3, wf1, 4);
    GSTP(wO0, wO1, wO2, wO3, gO0, gO1, 3, gE0, gE1, 4, 1); LDW(wO0, wO1, wO2, wO3, wf1, 5);
    GSTP(wE0, wE1, wE2, wE3, gE0, gE1, 4, gO0, gO1, 5, 1); LDW(wE0, wE1, wE2, wE3, wf1, 6);
    GSTP(wO0, wO1, wO2, wO3, gO0, gO1, 5, gE0, gE1, 6, 1); LDW(wO0, wO1, wO2, wO3, wf1, 7);
    GSTP(wE0, wE1, wE2, wE3, gE0, gE1, 6, gO0, gO1, 7, 1); LDW(wE0, wE1, wE2, wE3, wf1, 8);
    GSTP(wO0, wO1, wO2, wO3, gO0, gO1, 7, gE0, gE1, 8, 1); LDW(wO0, wO1, wO2, wO3, wf2, 0);
    GSTP(wE0, wE1, wE2, wE3, gE0, gE1, 8, gO0, gO1, 0, 0); LDW(wE0, wE1, wE2, wE3, wf2, 1);

    __syncthreads();  // all grid readers done before overwriting Abuf with X
    // epilogue 1: packed b64 writes at halves-split cols (no bias — folded)
    {
        const int qb = quad & 1, qh = quad >> 1;
        const int ce = 144 * qb + qh * 4;         // even j' = wv*4+j
        const int co = 144 * qb + (2 + qh) * 4;   // odd j'
        const int r16 = wv * 32;                  // (wv*2)*16
        *(bf16x4*)&Abuf[     lane16][ce + r16]      = pack4(a00);
        *(bf16x4*)&Abuf[16 + lane16][ce + r16]      = pack4(a10);
        *(bf16x4*)&Abuf[32 + lane16][ce + r16]      = pack4(a20);
        *(bf16x4*)&Abuf[48 + lane16][ce + r16]      = pack4(a30);
        *(bf16x4*)&Abuf[     lane16][co + r16]      = pack4(a01);
        *(bf16x4*)&Abuf[16 + lane16][co + r16]      = pack4(a11);
        *(bf16x4*)&Abuf[32 + lane16][co + r16]      = pack4(a21);
        *(bf16x4*)&Abuf[48 + lane16][co + r16]      = pack4(a31);
        *(bf16x4*)&Abuf[     lane16][ce + r16 + 16] = pack4(a02);
        *(bf16x4*)&Abuf[16 + lane16][ce + r16 + 16] = pack4(a12);
        *(bf16x4*)&Abuf[32 + lane16][ce + r16 + 16] = pack4(a22);
        *(bf16x4*)&Abuf[48 + lane16][ce + r16 + 16] = pack4(a32);
        *(bf16x4*)&Abuf[     lane16][co + r16 + 16] = pack4(a03);
        *(bf16x4*)&Abuf[16 + lane16][co + r16 + 16] = pack4(a13);
        *(bf16x4*)&Abuf[32 + lane16][co + r16 + 16] = pack4(a23);
        *(bf16x4*)&Abuf[48 + lane16][co + r16 + 16] = pack4(a33);
    }
    __syncthreads();

    ZACC4(0); ZACC4(1); ZACC4(2); ZACC4(3);
    LDG2(gE0, gE1, 0);

    // ---------- layer 2: W1[256x256] x X, 8 ksteps (k0 weights in wO) ----------
    GSTP(wO0, wO1, wO2, wO3, gE0, gE1, 0, gO0, gO1, 1, 1); LDW(wO0, wO1, wO2, wO3, wf2, 2);
    GSTP(wE0, wE1, wE2, wE3, gO0, gO1, 1, gE0, gE1, 2, 1); LDW(wE0, wE1, wE2, wE3, wf2, 3);
    GSTP(wO0, wO1, wO2, wO3, gE0, gE1, 2, gO0, gO1, 3, 1); LDW(wO0, wO1, wO2, wO3, wf2, 4);
    GSTP(wE0, wE1, wE2, wE3, gO0, gO1, 3, gE0, gE1, 4, 1); LDW(wE0, wE1, wE2, wE3, wf2, 5);
    GSTP(wO0, wO1, wO2, wO3, gE0, gE1, 4, gO0, gO1, 5, 1); LDW(wO0, wO1, wO2, wO3, wf2, 6);
    GSTP(wE0, wE1, wE2, wE3, gO0, gO1, 5, gE0, gE1, 6, 1); LDW(wE0, wE1, wE2, wE3, wf2, 7);
    GSTP(wO0, wO1, wO2, wO3, gE0, gE1, 6, gO0, gO1, 7, 1); wO0 = w2f[0 * 64 + lane];
    GSTP(wE0, wE1, wE2, wE3, gO0, gO1, 7, gE0, gE1, 0, 0); wE0 = w2f[1 * 64 + lane];

    __syncthreads();
    // epilogue 2: bias + gelu, packed b64 writes at halves-split cols
    {
        const int qb = quad & 1, qh = quad >> 1;
        const int ce = 144 * qb + qh * 4;
        const int co = 144 * qb + (2 + qh) * 4;
        const int r16 = wv * 32;
#define GEL4(x, bi) { bf16x4 v; v[0] = (__bf16)gelu_fast((x)[0] + (bi)[0]); \
        v[1] = (__bf16)gelu_fast((x)[1] + (bi)[1]); \
        v[2] = (__bf16)gelu_fast((x)[2] + (bi)[2]); \
        v[3] = (__bf16)gelu_fast((x)[3] + (bi)[3]); vv = v; }
        bf16x4 vv;
        const f32x4 bi0 = *(const f32x4*)&b1eff[(mb0 + 0) * 16 + q4];
        const f32x4 bi1 = *(const f32x4*)&b1eff[(mb0 + 1) * 16 + q4];
        const f32x4 bi2 = *(const f32x4*)&b1eff[(mb0 + 2) * 16 + q4];
        const f32x4 bi3 = *(const f32x4*)&b1eff[(mb0 + 3) * 16 + q4];
        GEL4(a00, bi0); *(bf16x4*)&Abuf[     lane16][ce + r16]      = vv;
        GEL4(a10, bi0); *(bf16x4*)&Abuf[16 + lane16][ce + r16]      = vv;
        GEL4(a20, bi0); *(bf16x4*)&Abuf[32 + lane16][ce + r16]      = vv;
        GEL4(a30, bi0); *(bf16x4*)&Abuf[48 + lane16][ce + r16]      = vv;
        GEL4(a01, bi1); *(bf16x4*)&Abuf[     lane16][co + r16]      = vv;
        GEL4(a11, bi1); *(bf16x4*)&Abuf[16 + lane16][co + r16]      = vv;
        GEL4(a21, bi1); *(bf16x4*)&Abuf[32 + lane16][co + r16]      = vv;
        GEL4(a31, bi1); *(bf16x4*)&Abuf[48 + lane16][co + r16]      = vv;
        GEL4(a02, bi2); *(bf16x4*)&Abuf[     lane16][ce + r16 + 16] = vv;
        GEL4(a12, bi2); *(bf16x4*)&Abuf[16 + lane16][ce + r16 + 16] = vv;
        GEL4(a22, bi2); *(bf16x4*)&Abuf[32 + lane16][ce + r16 + 16] = vv;
        GEL4(a32, bi2); *(bf16x4*)&Abuf[48 + lane16][ce + r16 + 16] = vv;
        GEL4(a03, bi3); *(bf16x4*)&Abuf[     lane16][co + r16 + 16] = vv;
        GEL4(a13, bi3); *(bf16x4*)&Abuf[16 + lane16][co + r16 + 16] = vv;
        GEL4(a23, bi3); *(bf16x4*)&Abuf[32 + lane16][co + r16 + 16] = vv;
        GEL4(a33, bi3); *(bf16x4*)&Abuf[48 + lane16][co + r16 + 16] = vv;
#undef GEL4
    }
    __syncthreads();

    // ---------- layer 3: W2[16x256] x Y, 8 ksteps; wave wv owns px-block wv ----------
    f32x4 acc3 = zf;
    {
        const int row3 = wv * 16 + lane16;
        bf16x8 y0, y1;
        LD1(y0, row3, 0);
        LD1(y1, row3, 1); acc3 = MF(wO0, y0, acc3); wO0 = w2f[2 * 64 + lane];
        LD1(y0, row3, 2); acc3 = MF(wE0, y1, acc3); wE0 = w2f[3 * 64 + lane];
        LD1(y1, row3, 3); acc3 = MF(wO0, y0, acc3); wO0 = w2f[4 * 64 + lane];
        LD1(y0, row3, 4); acc3 = MF(wE0, y1, acc3); wE0 = w2f[5 * 64 + lane];
        LD1(y1, row3, 5); acc3 = MF(wO0, y0, acc3); wO0 = w2f[6 * 64 + lane];
        LD1(y0, row3, 6); acc3 = MF(wE0, y1, acc3); wE0 = w2f[7 * 64 + lane];
        LD1(y1, row3, 7); acc3 = MF(wO0, y0, acc3);
                          acc3 = MF(wE0, y1, acc3);
    }

    // ---------- epilogue: rows 0..2 (quad 0) hold the 3 output channels ----------
    if (quad == 0) {
        const int pix = wv * 16 + lane16;
        const int X = X0 + pix;
        const float uy = ((cy + 1.f) * hn - 1.f) * 0.5f;
        const float fy = floorf(uy);
        const float wy = uy - fy;
        const int y0i = min(max((int)fy, 0), hn - 1);
        const int y1i = min(max((int)fy + 1, 0), hn - 1);
        const float cx = -1.f + 1.f / Wn + (2.f / Wn) * (float)X;
        const float ux = ((cx + 1.f) * wn - 1.f) * 0.5f;
        const float fx = floorf(ux);
        const float wx = ux - fx;
        const int x0i = min(max((int)fx, 0), wn - 1);
        const int x1i = min(max((int)fx + 1, 0), wn - 1);
        const float w00b = (1.f - wy) * (1.f - wx), w01b = (1.f - wy) * wx;
        const float w10b = wy * (1.f - wx), w11b = wy * wx;
#pragma unroll
        for (int r = 0; r < 3; r++) {
            const float* scb = sc + (b * 3 + r) * (hn * wn);
            const float samp = scb[y0i * wn + x0i] * w00b + scb[y0i * wn + x1i] * w01b
                             + scb[y1i * wn + x0i] * w10b + scb[y1i * wn + x1i] * w11b;
            out[((b * 3 + r) * Hn + Y) * Wn + X] = acc3[r] + b2v[r] + samp;
        }
    }
}

extern "C" void kernel_launch(void* const* d_in, const int* in_sizes, int n_in,
                              void* d_out, int out_size, void* d_ws, size_t ws_size,
                              hipStream_t stream)
{
    const float* feat = (const float*)d_in[0];
    const float* w00  = (const float*)d_in[1];
    const float* b00  = (const float*)d_in[2];
    const float* w1   = (const float*)d_in[3];
    const float* b1   = (const float*)d_in[4];
    const float* w2   = (const float*)d_in[5];
    const float* b2   = (const float*)d_in[6];
    const float* ws1  = (const float*)d_in[7];
    const float* bs1  = (const float*)d_in[8];
    const float* ws2  = (const float*)d_in[9];
    const float* bs2  = (const float*)d_in[10];
    float* out = (float*)d_out;

    __bf16* wb    = (__bf16*)d_ws;
    float* scbuf  = (float*)((char*)d_ws + SC_OFF_BYTES);
    float* b1eff  = (float*)((char*)d_ws + B1EFF_OFF_BYTES);

    prep_all<<<FRAG_BLOCKS + 1 + SC_BLOCKS, 256, 0, stream>>>(
        w00, w1, w2, b00, b1, feat, ws1, bs1, ws2, bs2, wb, b1eff, scbuf);
    liif_main<<<Bn * Hn * (Wn / TM), 256, 0, stream>>>(feat, b1eff, b2, wb, scbuf, out);
}